// Round 10
// baseline (263.663 us; speedup 1.0000x reference)
//
#include <hip/hip_runtime.h>

// RBF causal attention: out[m] = sum_{j<=m} exp(-0.125*||q_m - k_j||^2) * v_j
// B=2 H=16 S=2048 D=64, fp32 in/out.
// fp16 hi/lo-split QK (3 MFMAs ~ fp32 accuracy), fp16 PV with p scaled 2^14.
// R16 = R15 (63.1us; BN=128, 4-ntile interleaved body) + region-phased staging:
// R15 dropped R8's dbuf -> the 49.7KB stage was issued and immediately drained
// by __syncthreads every iter (~3k cy serial DMA). The tile is phase-disjoint
// (QK reads Khi/Klo only; exp/PV reads Vt/ksq only), so stage by region in the
// SAME single buffer:
//   phase A: issue Vt+ksq(jt) DMA || QK(jt) 48 MFMAs -> barrier (V ready)
//   phase B: issue Khi/Klo(jt+1) DMA || EXPP/PVF interleave -> barrier (K ready)
// Every DMA gets a full compute phase to land; 2 barriers/iter unchanged;
// LDS/occupancy/grid/L2 regime unchanged (R9/R11/R12 lessons).
// ksq staged with V (read in phase B; phase-B K-stage must not clobber it).
// Diag path uses unrolled if(w>=n) guards -- no dynamic acc indexing (rule 20).

constexpr int S_LEN = 2048;
constexpr int HD    = 64;
constexpr int BM    = 128;   // Q rows per block (4 waves x 32 rows)
constexpr int BN    = 128;   // K/V rows per tile (4 ntiles of 32)
constexpr float SCALE = 0.125f;
constexpr float LOG2E = 1.44269504088896f;
constexpr float C2    = 2.f * SCALE * LOG2E;   // coeff on qk term
constexpr int TS2 = 49664;   // ws bytes/tile: Khi 16K|Klo 16K|Vt 16K|ksq 512

typedef _Float16 half8  __attribute__((ext_vector_type(8)));
typedef _Float16 half4  __attribute__((ext_vector_type(4)));
typedef _Float16 half2v __attribute__((ext_vector_type(2)));
typedef float    f32x4  __attribute__((ext_vector_type(4)));
typedef float    f32x16 __attribute__((ext_vector_type(16)));
typedef unsigned int uint4v __attribute__((ext_vector_type(4)));
typedef unsigned int uint2v __attribute__((ext_vector_type(2)));

// ---------------- pass 1: preconvert K/V into LDS-image tiles in ws ----------
// Writer block x runs on XCD x&7; map so tile (bh,jt) is written from XCD
// bh>>2 -- the consumer's L2 slice. Grid: 32 bh x 16 jt = 512 blocks.
__global__ __launch_bounds__(256, 4)
void preconvert(const float* __restrict__ Kp, const float* __restrict__ Vp,
                char* __restrict__ ws) {
  const int x  = blockIdx.x;
  const int bh = (x & 7) * 4 + ((x >> 3) & 3);
  const int jt = x >> 5;                        // 0..15
  const int t  = threadIdx.x;
  const int w  = t >> 6, lane = t & 63;

  char* img = ws + (size_t)(bh * 16 + jt) * TS2;
  half8* imgKh = (half8*)img;           // [128 rows][8 chunks] swizzled, 1024 half8
  half8* imgKl = imgKh + 1024;          // +16KB
  half8* imgVt = imgKh + 2048;          // +32KB: [64 rows(d)][16 chunks] swizzled
  float* ksqp  = (float*)(img + 49152); // 128 floats

  const float* Kt = Kp + ((size_t)bh * S_LEN + jt * BN) * HD;
  const float* Vt = Vp + ((size_t)bh * S_LEN + jt * BN) * HD;

  #pragma unroll
  for (int i = 0; i < 8; ++i) {
    const int id  = t + 256 * i;
    const int row = id >> 4;            // 0..127
    const int d4  = id & 15;
    const f32x4 f = *(const f32x4*)(Kt + row * HD + d4 * 4);
    half4 hv, lv;
    float ss = 0.f;
    #pragma unroll
    for (int c = 0; c < 4; ++c) {
      const float fv = f[c];
      const _Float16 hi = (_Float16)fv;
      hv[c] = hi;
      lv[c] = (_Float16)(fv - (float)hi);
      ss += fv * fv;
    }
    const int idx8 = (row << 3) + ((d4 >> 1) ^ (row & 7));   // <= 1023
    ((half4*)&imgKh[idx8])[d4 & 1] = hv;
    ((half4*)&imgKl[idx8])[d4 & 1] = lv;
    #pragma unroll
    for (int m = 1; m < 16; m <<= 1) ss += __shfl_xor(ss, m);
    if ((t & 15) == 0) ksqp[row] = ss * (SCALE * LOG2E) - 14.0f;  // bias folded
  }
  // V transpose: lane holds col d=lane (row of V^T); wave w covers k-rows
  // w*32..w*32+31 = chunks w*4..w*4+3 of V^T row d.
  float vr[32];
  #pragma unroll
  for (int i = 0; i < 32; ++i) vr[i] = Vt[(w * 32 + i) * HD + lane];
  #pragma unroll
  for (int j = 0; j < 4; ++j) {
    half8 v;
    #pragma unroll
    for (int e = 0; e < 8; ++e) v[e] = (_Float16)vr[j * 8 + e];
    imgVt[(lane << 4) + ((w * 4 + j) ^ (lane & 7))] = v;     // <= 1023
  }
}

// ---------------- main kernel ------------------------------------------------
__global__ __launch_bounds__(256, 3)
void rbf_causal_attn(const float* __restrict__ Qp, const char* __restrict__ ws,
                     float* __restrict__ Op) {
  __shared__ __align__(16) char sTile[TS2];    // Khi|Klo|Vt|ksq image

  const int x    = blockIdx.x;                 // 0..767
  const int xcd  = x & 7;
  const int idx  = x >> 3;                     // 0..95
  const int bh   = xcd * 4 + (idx & 3);        // 4 bh per XCD (L2 reuse of ws)
  const int a    = idx >> 2;                   // arc 0..23
  const int t    = threadIdx.x;
  const int w    = t >> 6;
  const int lane = t & 63;
  const int l31  = lane & 31;
  const int l5   = lane >> 5;                  // 0/1

  // 136 j-iters per bh (qt=15..0, qt+1 tiles each); 16 arcs x 6 + 8 arcs x 5
  const int start = (a < 16) ? 6 * a : 96 + 5 * (a - 16);
  const int len   = (a < 16) ? 6 : 5;

  // flattened (qt descending, jt ascending) -> (qt, jt)
  int rem = start, qt = 15;
  while (rem >= qt + 1) { rem -= qt + 1; --qt; }
  int jt = rem;

  const char* wsb = ws + (size_t)bh * 16 * TS2;

  const half8* bKh  = (const half8*)sTile;     // 1024 half8
  const half8* bKl  = bKh + 1024;              // +16KB
  const half8* bVt  = bKh + 2048;              // +32KB
  const float* bksq = (const float*)(sTile + 49152);

  half8 qh[4], ql[4];   // B-operand Q frags: lane holds row w*32+l31, d-chunk ks*16+l5*8
  float qsq;            // SCALE*LOG2E*|q_row|^2
  f32x16 oacc[2];       // O accumulator (x 2^14), dtile 0/1
  #pragma unroll
  for (int d = 0; d < 2; ++d)
    #pragma unroll
    for (int e = 0; e < 16; ++e) oacc[d][e] = 0.f;

  auto load_q = [&](int qtile) {
    const float* Qg = Qp + ((size_t)bh * S_LEN + (size_t)qtile * BM + w * 32 + l31) * HD;
    float ss = 0.f;
    #pragma unroll
    for (int ks = 0; ks < 4; ++ks) {
      const int d0 = ks * 16 + l5 * 8;
      const f32x4 fa = *(const f32x4*)(Qg + d0);
      const f32x4 fb = *(const f32x4*)(Qg + d0 + 4);
      half8 h, l;
      #pragma unroll
      for (int c = 0; c < 4; ++c) {
        const float va = fa[c], vb = fb[c];
        const _Float16 ha = (_Float16)va, hb = (_Float16)vb;
        h[c] = ha;  h[c + 4] = hb;
        l[c] = (_Float16)(va - (float)ha);
        l[c + 4] = (_Float16)(vb - (float)hb);
        ss += va * va + vb * vb;
      }
      qh[ks] = h;  ql[ks] = l;
    }
    ss += __shfl_xor(ss, 32);   // combine l5 halves -> full row sum
    qsq = ss * (SCALE * LOG2E);
  };

  auto flush = [&](int qtile) {
    #pragma unroll
    for (int dt = 0; dt < 2; ++dt)
      #pragma unroll
      for (int r = 0; r < 16; ++r) {
        const int row = qtile * BM + w * 32 + (r & 3) + 8 * (r >> 2) + 4 * l5;
        atomicAdd(Op + ((size_t)bh * S_LEN + row) * HD + dt * 32 + l31,
                  oacc[dt][r] * 6.103515625e-05f);   // * 2^-14
      }
  };

  auto zacc = [&]() {
    #pragma unroll
    for (int d = 0; d < 2; ++d)
      #pragma unroll
      for (int e = 0; e < 16; ++e) oacc[d][e] = 0.f;
  };

  // K-region stage: Khi|Klo of tile jtile, bytes [0,32K). 8x1KB per wave.
  auto stageK = [&](int jtile) {
    const char* gt = wsb + (size_t)jtile * TS2;
    #pragma unroll
    for (int i = 0; i < 8; ++i) {
      const int off = w * 8192 + i * 1024;
      __builtin_amdgcn_global_load_lds((const unsigned int*)(gt + off + lane * 16),
                                       (unsigned int*)(sTile + off), 16, 0, 0);
    }
  };

  // V-region stage: Vt bytes [32K,48K) (4x1KB per wave) + ksq 512B (w0).
  auto stageV = [&](int jtile) {
    const char* gt = wsb + (size_t)jtile * TS2;
    #pragma unroll
    for (int i = 0; i < 4; ++i) {
      const int off = 32768 + w * 4096 + i * 1024;
      __builtin_amdgcn_global_load_lds((const unsigned int*)(gt + off + lane * 16),
                                       (unsigned int*)(sTile + off), 16, 0, 0);
    }
    if (w == 0 && lane < 32)
      __builtin_amdgcn_global_load_lds((const unsigned int*)(gt + 49152 + lane * 16),
                                       (unsigned int*)(sTile + 49152), 16, 0, 0);
  };

  // pack two fp32 -> one u32 of 2 x fp16 (RNE, same numerics as before)
  auto pk = [&](float xx, float yy) -> unsigned int {
    half2v h;
    h[0] = (_Float16)xx;
    h[1] = (_Float16)yy;
    return __builtin_bit_cast(unsigned int, h);
  };

  // ---- building blocks (per 32-row ntile) ----
  auto QK = [&](int ntile, f32x16& acc) {
    #pragma unroll
    for (int e = 0; e < 16; ++e) acc[e] = 0.f;
    const int rr = ntile * 32 + l31;
    #pragma unroll
    for (int ks = 0; ks < 4; ++ks) {
      const int ch = (2 * ks + l5) ^ (rr & 7);
      const half8 kh = bKh[(rr << 3) + ch];
      const half8 kl = bKl[(rr << 3) + ch];
      acc = __builtin_amdgcn_mfma_f32_32x32x16_f16(kh, qh[ks], acc, 0, 0, 0);
      acc = __builtin_amdgcn_mfma_f32_32x32x16_f16(kh, ql[ks], acc, 0, 0, 0);
      acc = __builtin_amdgcn_mfma_f32_32x32x16_f16(kl, qh[ks], acc, 0, 0, 0);
    }
  };

  // exp2 + optional causal mask (valid only for ntile==w on jt==qt tiles,
  // where the condition reduces to k_local > l31) + pack into PV A-frags.
  // acc[r] = P[k_loc=(r&3)+8*(r>>2)+4*l5][q=l31]; permlane32_swap(vdst=A,vsrc=B)
  // swaps VDST.hi32lanes <-> VSRC.lo32lanes -> pa = {newA0,newA1,newB0,newB1}
  // = P[q=l31][k=16*ks2+8*l5+0..7].
  auto EXPP = [&](int ntile, f32x16& acc, half8& pa0, half8& pa1, bool domask) {
    #pragma unroll
    for (int g = 0; g < 4; ++g) {
      const f32x4 k4 = *(const f32x4*)(bksq + ntile * 32 + 8 * g + 4 * l5);
      #pragma unroll
      for (int rr2 = 0; rr2 < 4; ++rr2) {
        const int reg = g * 4 + rr2;
        const float lg = __builtin_fmaf(C2, acc[reg], -k4[rr2]) - qsq;
        float pv = __builtin_amdgcn_exp2f(lg);
        if (domask) {
          const int nloc = 8 * g + 4 * l5 + rr2;
          if (nloc > l31) pv = 0.f;
        }
        acc[reg] = pv;
      }
    }
    #pragma unroll
    for (int ks2 = 0; ks2 < 2; ++ks2) {
      const unsigned int a0 = pk(acc[8 * ks2 + 0], acc[8 * ks2 + 1]);
      const unsigned int a1 = pk(acc[8 * ks2 + 2], acc[8 * ks2 + 3]);
      const unsigned int b0 = pk(acc[8 * ks2 + 4], acc[8 * ks2 + 5]);
      const unsigned int b1 = pk(acc[8 * ks2 + 6], acc[8 * ks2 + 7]);
      const uint2v r0 = __builtin_amdgcn_permlane32_swap(a0, b0, false, false);
      const uint2v r1 = __builtin_amdgcn_permlane32_swap(a1, b1, false, false);
      uint4v wv;
      wv[0] = r0[0];  wv[1] = r1[0];
      wv[2] = r0[1];  wv[3] = r1[1];
      if (ks2 == 0) pa0 = __builtin_bit_cast(half8, wv);
      else          pa1 = __builtin_bit_cast(half8, wv);
    }
  };

  auto PVF = [&](int ntile, half8 pa0v, half8 pa1v) {
    #pragma unroll
    for (int ks2 = 0; ks2 < 2; ++ks2) {
      const half8 pa = ks2 ? pa1v : pa0v;
      const int ks = ntile * 2 + ks2;
      #pragma unroll
      for (int dt = 0; dt < 2; ++dt) {
        const int rr = dt * 32 + l31;
        const half8 vt = bVt[(rr << 4) + ((2 * ks + l5) ^ (rr & 7))];
        oacc[dt] = __builtin_amdgcn_mfma_f32_32x32x16_f16(pa, vt, oacc[dt], 0, 0, 0);
      }
    }
  };

  load_q(qt);
  stageK(jt);
  __syncthreads();             // K(j0) ready

  bool newq = false;
  #pragma unroll 1
  for (int step = 0; step < len; ++step) {
    // next-step tile indices (uniform across block)
    int jn = jt + 1, qn = qt;
    const bool cross = (jn > qt);
    if (cross) { jn = 0; qn = qt - 1; }
    const bool diag = (jt == qt);

    // ---- phase A: V+ksq(jt) DMA || QK(jt) ----
    stageV(jt);
    if (newq) { flush(qt + 1); zacc(); load_q(qt); newq = false; }

    f32x16 acc0, acc1, acc2, acc3;
    if (!diag) {
      QK(0, acc0); QK(1, acc1); QK(2, acc2); QK(3, acc3);
    } else {
      QK(0, acc0);
      if (w >= 1) QK(1, acc1);
      if (w >= 2) QK(2, acc2);
      if (w >= 3) QK(3, acc3);
    }
    __syncthreads();   // V+ksq ready (own DMA drained + barrier); K region free

    // ---- phase B: K(jn) DMA || exp+pack+PV (VALU || MFMA interleave) ----
    if (step + 1 < len) stageK(jn);

    half8 pa0, pa1, pb0, pb1;
    if (!diag) {
      EXPP(0, acc0, pa0, pa1, false);
      EXPP(1, acc1, pb0, pb1, false);  PVF(0, pa0, pa1);
      EXPP(2, acc2, pa0, pa1, false);  PVF(1, pb0, pb1);
      EXPP(3, acc3, pb0, pb1, false);  PVF(2, pa0, pa1);
                                       PVF(3, pb0, pb1);
    } else {
      // diagonal tile (jt==qt): ntile>w fully masked -> skipped;
      // ntile==w needs the per-element causal mask
      EXPP(0, acc0, pa0, pa1, w == 0);  PVF(0, pa0, pa1);
      if (w >= 1) { EXPP(1, acc1, pa0, pa1, w == 1);  PVF(1, pa0, pa1); }
      if (w >= 2) { EXPP(2, acc2, pa0, pa1, w == 2);  PVF(2, pa0, pa1); }
      if (w >= 3) { EXPP(3, acc3, pa0, pa1, w == 3);  PVF(3, pa0, pa1); }
    }
    __syncthreads();   // K(jn) ready for next iter; V region free

    jt = jn;
    if (cross) { qt = qn; newq = true; }
  }
  flush(newq ? qt + 1 : qt);
}

extern "C" void kernel_launch(void* const* d_in, const int* in_sizes, int n_in,
                              void* d_out, int out_size, void* d_ws, size_t ws_size,
                              hipStream_t stream) {
  const float* q = (const float*)d_in[0];
  const float* k = (const float*)d_in[1];
  const float* v = (const float*)d_in[2];
  float* o = (float*)d_out;
  hipMemsetAsync(d_out, 0, (size_t)out_size * sizeof(float), stream);
  preconvert<<<dim3(512), dim3(256), 0, stream>>>(k, v, (char*)d_ws);
  rbf_causal_attn<<<dim3(768), dim3(256), 0, stream>>>(q, (const char*)d_ws, o);
}

// Round 11
// 219.742 us; speedup vs baseline: 1.1999x; 1.1999x over previous
//
#include <hip/hip_runtime.h>

// RBF causal attention: out[m] = sum_{j<=m} exp(-0.125*||q_m - k_j||^2) * v_j
// B=2 H=16 S=2048 D=64, fp32 in/out.
// fp16 hi/lo-split QK (3 MFMAs ~ fp32 accuracy), fp16 PV with p scaled 2^14.
// R17 = R15 (63.1us, best) + PV accumulator chain split ONLY:
// R8->R15 showed halving iteration count bought just 5% -> per-iter fixed
// overhead is not the stall. The unattacked scaler: oacc dependency chains --
// each oacc[dt] received 8 serially-dependent PV MFMAs/iter (~320-500cy spine,
// ~50K cy/block over the kernel, 3 waves/SIMD to hide it). Now 4 accumulators
// (ntile 0,2 -> A-pair; 1,3 -> B-pair): 4 independent chains of depth 4/iter,
// merged A+B only in flush (32 fp32 adds per FLUSH -- unlike R10's failed
// per-iteration QK merge). QK uses 4 independent accs (R16 body shape, 84 VGPR).
// Staging schedule, barriers, grid, LDS layout: byte-identical to R15
// (R9/R11/R12/R16 all proved the staging/L2 regime must not be touched).

constexpr int S_LEN = 2048;
constexpr int HD    = 64;
constexpr int BM    = 128;   // Q rows per block (4 waves x 32 rows)
constexpr int BN    = 128;   // K/V rows per tile (4 ntiles of 32)
constexpr float SCALE = 0.125f;
constexpr float LOG2E = 1.44269504088896f;
constexpr float C2    = 2.f * SCALE * LOG2E;   // coeff on qk term
constexpr int TS2 = 49664;   // ws bytes/tile: Khi 16K|Klo 16K|Vt 16K|ksq 512

typedef _Float16 half8  __attribute__((ext_vector_type(8)));
typedef _Float16 half4  __attribute__((ext_vector_type(4)));
typedef _Float16 half2v __attribute__((ext_vector_type(2)));
typedef float    f32x4  __attribute__((ext_vector_type(4)));
typedef float    f32x16 __attribute__((ext_vector_type(16)));
typedef unsigned int uint4v __attribute__((ext_vector_type(4)));
typedef unsigned int uint2v __attribute__((ext_vector_type(2)));

// ---------------- pass 1: preconvert K/V into LDS-image tiles in ws ----------
// Writer block x runs on XCD x&7; map so tile (bh,jt) is written from XCD
// bh>>2 -- the consumer's L2 slice. Grid: 32 bh x 16 jt = 512 blocks.
__global__ __launch_bounds__(256, 4)
void preconvert(const float* __restrict__ Kp, const float* __restrict__ Vp,
                char* __restrict__ ws) {
  const int x  = blockIdx.x;
  const int bh = (x & 7) * 4 + ((x >> 3) & 3);
  const int jt = x >> 5;                        // 0..15
  const int t  = threadIdx.x;
  const int w  = t >> 6, lane = t & 63;

  char* img = ws + (size_t)(bh * 16 + jt) * TS2;
  half8* imgKh = (half8*)img;           // [128 rows][8 chunks] swizzled, 1024 half8
  half8* imgKl = imgKh + 1024;          // +16KB
  half8* imgVt = imgKh + 2048;          // +32KB: [64 rows(d)][16 chunks] swizzled
  float* ksqp  = (float*)(img + 49152); // 128 floats

  const float* Kt = Kp + ((size_t)bh * S_LEN + jt * BN) * HD;
  const float* Vt = Vp + ((size_t)bh * S_LEN + jt * BN) * HD;

  #pragma unroll
  for (int i = 0; i < 8; ++i) {
    const int id  = t + 256 * i;
    const int row = id >> 4;            // 0..127
    const int d4  = id & 15;
    const f32x4 f = *(const f32x4*)(Kt + row * HD + d4 * 4);
    half4 hv, lv;
    float ss = 0.f;
    #pragma unroll
    for (int c = 0; c < 4; ++c) {
      const float fv = f[c];
      const _Float16 hi = (_Float16)fv;
      hv[c] = hi;
      lv[c] = (_Float16)(fv - (float)hi);
      ss += fv * fv;
    }
    const int idx8 = (row << 3) + ((d4 >> 1) ^ (row & 7));   // <= 1023
    ((half4*)&imgKh[idx8])[d4 & 1] = hv;
    ((half4*)&imgKl[idx8])[d4 & 1] = lv;
    #pragma unroll
    for (int m = 1; m < 16; m <<= 1) ss += __shfl_xor(ss, m);
    if ((t & 15) == 0) ksqp[row] = ss * (SCALE * LOG2E) - 14.0f;  // bias folded
  }
  // V transpose: lane holds col d=lane (row of V^T); wave w covers k-rows
  // w*32..w*32+31 = chunks w*4..w*4+3 of V^T row d.
  float vr[32];
  #pragma unroll
  for (int i = 0; i < 32; ++i) vr[i] = Vt[(w * 32 + i) * HD + lane];
  #pragma unroll
  for (int j = 0; j < 4; ++j) {
    half8 v;
    #pragma unroll
    for (int e = 0; e < 8; ++e) v[e] = (_Float16)vr[j * 8 + e];
    imgVt[(lane << 4) + ((w * 4 + j) ^ (lane & 7))] = v;     // <= 1023
  }
}

// ---------------- main kernel ------------------------------------------------
__global__ __launch_bounds__(256, 3)
void rbf_causal_attn(const float* __restrict__ Qp, const char* __restrict__ ws,
                     float* __restrict__ Op) {
  __shared__ __align__(16) char sTile[TS2];    // Khi|Klo|Vt|ksq image

  const int x    = blockIdx.x;                 // 0..767
  const int xcd  = x & 7;
  const int idx  = x >> 3;                     // 0..95
  const int bh   = xcd * 4 + (idx & 3);        // 4 bh per XCD (L2 reuse of ws)
  const int a    = idx >> 2;                   // arc 0..23
  const int t    = threadIdx.x;
  const int w    = t >> 6;
  const int lane = t & 63;
  const int l31  = lane & 31;
  const int l5   = lane >> 5;                  // 0/1

  // 136 j-iters per bh (qt=15..0, qt+1 tiles each); 16 arcs x 6 + 8 arcs x 5
  const int start = (a < 16) ? 6 * a : 96 + 5 * (a - 16);
  const int len   = (a < 16) ? 6 : 5;

  // flattened (qt descending, jt ascending) -> (qt, jt)
  int rem = start, qt = 15;
  while (rem >= qt + 1) { rem -= qt + 1; --qt; }
  int jt = rem;

  const char* wsb = ws + (size_t)bh * 16 * TS2;

  const half8* bKh  = (const half8*)sTile;     // 1024 half8
  const half8* bKl  = bKh + 1024;              // +16KB
  const half8* bVt  = bKh + 2048;              // +32KB
  const float* bksq = (const float*)(sTile + 49152);

  half8 qh[4], ql[4];   // B-operand Q frags: lane holds row w*32+l31, d-chunk ks*16+l5*8
  float qsq;            // SCALE*LOG2E*|q_row|^2
  // O accumulators (x 2^14): A-pair takes ntiles 0,2; B-pair ntiles 1,3.
  // 4 independent PV chains of depth 4/iter (was 2 chains of depth 8).
  f32x16 oA0, oA1, oB0, oB1;
  #pragma unroll
  for (int e = 0; e < 16; ++e) { oA0[e] = 0.f; oA1[e] = 0.f; oB0[e] = 0.f; oB1[e] = 0.f; }

  auto load_q = [&](int qtile) {
    const float* Qg = Qp + ((size_t)bh * S_LEN + (size_t)qtile * BM + w * 32 + l31) * HD;
    float ss = 0.f;
    #pragma unroll
    for (int ks = 0; ks < 4; ++ks) {
      const int d0 = ks * 16 + l5 * 8;
      const f32x4 fa = *(const f32x4*)(Qg + d0);
      const f32x4 fb = *(const f32x4*)(Qg + d0 + 4);
      half8 h, l;
      #pragma unroll
      for (int c = 0; c < 4; ++c) {
        const float va = fa[c], vb = fb[c];
        const _Float16 ha = (_Float16)va, hb = (_Float16)vb;
        h[c] = ha;  h[c + 4] = hb;
        l[c] = (_Float16)(va - (float)ha);
        l[c + 4] = (_Float16)(vb - (float)hb);
        ss += va * va + vb * vb;
      }
      qh[ks] = h;  ql[ks] = l;
    }
    ss += __shfl_xor(ss, 32);   // combine l5 halves -> full row sum
    qsq = ss * (SCALE * LOG2E);
  };

  auto flush = [&](int qtile) {
    #pragma unroll
    for (int dt = 0; dt < 2; ++dt)
      #pragma unroll
      for (int r = 0; r < 16; ++r) {
        const float vA = dt ? oA1[r] : oA0[r];
        const float vB = dt ? oB1[r] : oB0[r];
        const int row = qtile * BM + w * 32 + (r & 3) + 8 * (r >> 2) + 4 * l5;
        atomicAdd(Op + ((size_t)bh * S_LEN + row) * HD + dt * 32 + l31,
                  (vA + vB) * 6.103515625e-05f);   // * 2^-14
      }
  };

  auto zacc = [&]() {
    #pragma unroll
    for (int e = 0; e < 16; ++e) { oA0[e] = 0.f; oA1[e] = 0.f; oB0[e] = 0.f; oB1[e] = 0.f; }
  };

  // issue global->LDS DMA of tile jtile (drained by the following barrier)
  auto stage = [&](int jtile) {
    const char* gt = wsb + (size_t)jtile * TS2;
    #pragma unroll
    for (int i = 0; i < 12; ++i) {            // 48KB K+V
      const int off = w * 12288 + i * 1024;
      __builtin_amdgcn_global_load_lds((const unsigned int*)(gt + off + lane * 16),
                                       (unsigned int*)(sTile + off), 16, 0, 0);
    }
    if (w == 0 && lane < 32)                  // ksq 512B
      __builtin_amdgcn_global_load_lds((const unsigned int*)(gt + 49152 + lane * 16),
                                       (unsigned int*)(sTile + 49152), 16, 0, 0);
  };

  // pack two fp32 -> one u32 of 2 x fp16 (RNE, same numerics as before)
  auto pk = [&](float xx, float yy) -> unsigned int {
    half2v h;
    h[0] = (_Float16)xx;
    h[1] = (_Float16)yy;
    return __builtin_bit_cast(unsigned int, h);
  };

  // ---- building blocks (per 32-row ntile) ----
  auto QK = [&](int ntile, f32x16& acc) {
    #pragma unroll
    for (int e = 0; e < 16; ++e) acc[e] = 0.f;
    const int rr = ntile * 32 + l31;
    #pragma unroll
    for (int ks = 0; ks < 4; ++ks) {
      const int ch = (2 * ks + l5) ^ (rr & 7);
      const half8 kh = bKh[(rr << 3) + ch];
      const half8 kl = bKl[(rr << 3) + ch];
      acc = __builtin_amdgcn_mfma_f32_32x32x16_f16(kh, qh[ks], acc, 0, 0, 0);
      acc = __builtin_amdgcn_mfma_f32_32x32x16_f16(kh, ql[ks], acc, 0, 0, 0);
      acc = __builtin_amdgcn_mfma_f32_32x32x16_f16(kl, qh[ks], acc, 0, 0, 0);
    }
  };

  // exp2 + optional causal mask (valid only for ntile==w on jt==qt tiles,
  // where the condition reduces to k_local > l31) + pack into PV A-frags.
  // acc[r] = P[k_loc=(r&3)+8*(r>>2)+4*l5][q=l31]; permlane32_swap(vdst=A,vsrc=B)
  // swaps VDST.hi32lanes <-> VSRC.lo32lanes -> pa = {newA0,newA1,newB0,newB1}
  // = P[q=l31][k=16*ks2+8*l5+0..7].
  auto EXPP = [&](int ntile, f32x16& acc, half8& pa0, half8& pa1, bool domask) {
    #pragma unroll
    for (int g = 0; g < 4; ++g) {
      const f32x4 k4 = *(const f32x4*)(bksq + ntile * 32 + 8 * g + 4 * l5);
      #pragma unroll
      for (int rr2 = 0; rr2 < 4; ++rr2) {
        const int reg = g * 4 + rr2;
        const float lg = __builtin_fmaf(C2, acc[reg], -k4[rr2]) - qsq;
        float pv = __builtin_amdgcn_exp2f(lg);
        if (domask) {
          const int nloc = 8 * g + 4 * l5 + rr2;
          if (nloc > l31) pv = 0.f;
        }
        acc[reg] = pv;
      }
    }
    #pragma unroll
    for (int ks2 = 0; ks2 < 2; ++ks2) {
      const unsigned int a0 = pk(acc[8 * ks2 + 0], acc[8 * ks2 + 1]);
      const unsigned int a1 = pk(acc[8 * ks2 + 2], acc[8 * ks2 + 3]);
      const unsigned int b0 = pk(acc[8 * ks2 + 4], acc[8 * ks2 + 5]);
      const unsigned int b1 = pk(acc[8 * ks2 + 6], acc[8 * ks2 + 7]);
      const uint2v r0 = __builtin_amdgcn_permlane32_swap(a0, b0, false, false);
      const uint2v r1 = __builtin_amdgcn_permlane32_swap(a1, b1, false, false);
      uint4v wv;
      wv[0] = r0[0];  wv[1] = r1[0];
      wv[2] = r0[1];  wv[3] = r1[1];
      if (ks2 == 0) pa0 = __builtin_bit_cast(half8, wv);
      else          pa1 = __builtin_bit_cast(half8, wv);
    }
  };

  // PV into an explicit accumulator pair (od0/od1 = dtile 0/1 of that pair)
  auto PVF = [&](int ntile, half8 pa0v, half8 pa1v, f32x16& od0, f32x16& od1) {
    #pragma unroll
    for (int ks2 = 0; ks2 < 2; ++ks2) {
      const half8 pa = ks2 ? pa1v : pa0v;
      const int ks = ntile * 2 + ks2;
      {
        const int rr = l31;                  // dt 0
        const half8 vt = bVt[(rr << 4) + ((2 * ks + l5) ^ (rr & 7))];
        od0 = __builtin_amdgcn_mfma_f32_32x32x16_f16(pa, vt, od0, 0, 0, 0);
      }
      {
        const int rr = 32 + l31;             // dt 1
        const half8 vt = bVt[(rr << 4) + ((2 * ks + l5) ^ (rr & 7))];
        od1 = __builtin_amdgcn_mfma_f32_32x32x16_f16(pa, vt, od1, 0, 0, 0);
      }
    }
  };

  load_q(qt);

  bool newq = false;
  #pragma unroll 1
  for (int step = 0; step < len; ++step) {
    stage(jt);   // previous iteration's end barrier protects sTile

    // q-tile boundary bookkeeping: overlaps the in-flight DMA
    if (newq) { flush(qt + 1); zacc(); load_q(qt); newq = false; }

    __syncthreads();   // drains vmcnt -> tile image ready

    if (jt < qt) {
      // ---- clean tile: 4 independent QK chains, then interleaved exp/PV;
      //      PV split across A/B accumulator pairs (4 chains of depth 4) ----
      f32x16 acc0, acc1, acc2, acc3;
      half8 pa0, pa1, pb0, pb1;
      QK(0, acc0);
      QK(1, acc1);  EXPP(0, acc0, pa0, pa1, false);
      QK(2, acc2);  EXPP(1, acc1, pb0, pb1, false);  PVF(0, pa0, pa1, oA0, oA1);
      QK(3, acc3);  EXPP(2, acc2, pa0, pa1, false);  PVF(1, pb0, pb1, oB0, oB1);
                    EXPP(3, acc3, pb0, pb1, false);  PVF(2, pa0, pa1, oA0, oA1);
                                                     PVF(3, pb0, pb1, oB0, oB1);
    } else {
      // ---- diagonal tile (jt==qt): ntile>w fully masked -> skipped;
      //      ntile==w needs the per-element causal mask ----
      f32x16 acc;
      half8 pa0, pa1;
      QK(0, acc);
      EXPP(0, acc, pa0, pa1, w == 0);
      PVF(0, pa0, pa1, oA0, oA1);
      if (w >= 1) { QK(1, acc); EXPP(1, acc, pa0, pa1, w == 1); PVF(1, pa0, pa1, oB0, oB1); }
      if (w >= 2) { QK(2, acc); EXPP(2, acc, pa0, pa1, w == 2); PVF(2, pa0, pa1, oA0, oA1); }
      if (w >= 3) { QK(3, acc); EXPP(3, acc, pa0, pa1, w == 3); PVF(3, pa0, pa1, oB0, oB1); }
    }

    __syncthreads();   // all waves done reading sTile before next stage

    ++jt;
    if (jt > qt) { jt = 0; --qt; newq = true; }
  }
  flush(newq ? qt + 1 : qt);
}

extern "C" void kernel_launch(void* const* d_in, const int* in_sizes, int n_in,
                              void* d_out, int out_size, void* d_ws, size_t ws_size,
                              hipStream_t stream) {
  const float* q = (const float*)d_in[0];
  const float* k = (const float*)d_in[1];
  const float* v = (const float*)d_in[2];
  float* o = (float*)d_out;
  hipMemsetAsync(d_out, 0, (size_t)out_size * sizeof(float), stream);
  preconvert<<<dim3(512), dim3(256), 0, stream>>>(k, v, (char*)d_ws);
  rbf_causal_attn<<<dim3(768), dim3(256), 0, stream>>>(q, (const char*)d_ws, o);
}

// Round 12
// 148.130 us; speedup vs baseline: 1.7799x; 1.4834x over previous
//
#include <hip/hip_runtime.h>

// RBF causal attention: out[m] = sum_{j<=m} exp(-0.125*||q_m - k_j||^2) * v_j
// B=2 H=16 S=2048 D=64, fp32 in/out.
// fp16 hi/lo-split QK (3 MFMAs ~ fp32 accuracy), fp16 PV with p scaled 2^14.
// R18 = R15 (63.1us best) + chunk-major K/V LDS layout (conflict-free reads):
// R15's K-frag read addr = rr*128 + (ch^(rr&7))*16 has lane stride 128B ->
// every lane's chunk base is bank-0-aligned; the XOR spreads 32 lanes over
// only 8 chunk slots -> 4-WAY bank conflict on every ds_read_b128 (QK and PV);
// SQ_LDS_BANK_CONFLICT 3.19M ~= 12k LDS-pipe cy/CU, and the LDS pipe is
// CU-shared by all 12 waves (burst-issued right after the barrier).
// Fix: store K[chunk][row], V^T[chunk][row] -> a wave reads two contiguous
// 512B runs (rr*16 within a chunk plane) = canonical conflict-free b128.
// Stage DMA copies bytes blindly -> unchanged. Everything else = R15.
// R17 post-mortem: 4 QK + 4 O f32x16 accs -> scratch spill (VGPR stayed 84,
// FETCH/WRITE +177/+183MB symmetric = spill round-trips thrashing L2).
// At 3 waves/SIMD the budget holds ~6 live f32x16 max; O-split excluded.
// Also excluded: staging/grid reshape (R9/11/12/16), QK chain split (R10),
// counted vmcnt (R13).

constexpr int S_LEN = 2048;
constexpr int HD    = 64;
constexpr int BM    = 128;   // Q rows per block (4 waves x 32 rows)
constexpr int BN    = 128;   // K/V rows per tile (4 ntiles of 32)
constexpr float SCALE = 0.125f;
constexpr float LOG2E = 1.44269504088896f;
constexpr float C2    = 2.f * SCALE * LOG2E;   // coeff on qk term
constexpr int TS2 = 49664;   // ws bytes/tile: Khi 16K|Klo 16K|Vt 16K|ksq 512

typedef _Float16 half8  __attribute__((ext_vector_type(8)));
typedef _Float16 half4  __attribute__((ext_vector_type(4)));
typedef _Float16 half2v __attribute__((ext_vector_type(2)));
typedef float    f32x4  __attribute__((ext_vector_type(4)));
typedef float    f32x16 __attribute__((ext_vector_type(16)));
typedef unsigned int uint4v __attribute__((ext_vector_type(4)));
typedef unsigned int uint2v __attribute__((ext_vector_type(2)));

// ---------------- pass 1: preconvert K/V into LDS-image tiles in ws ----------
// Writer block x runs on XCD x&7; map so tile (bh,jt) is written from XCD
// bh>>2 -- the consumer's L2 slice. Grid: 32 bh x 16 jt = 512 blocks.
// Image layout (half8 units), CHUNK-MAJOR:
//   Khi[c][r] at c*128+r (c=0..7 d-chunks, r=0..127 k-rows)      [0,16K)
//   Klo[c][r] at 1024 + c*128+r                                  [16K,32K)
//   Vt [c][r] at 2048 + c*64+r  (c=0..15 k-chunks, r=0..63 d)    [32K,48K)
//   ksq 128 floats at byte 49152.
__global__ __launch_bounds__(256, 4)
void preconvert(const float* __restrict__ Kp, const float* __restrict__ Vp,
                char* __restrict__ ws) {
  const int x  = blockIdx.x;
  const int bh = (x & 7) * 4 + ((x >> 3) & 3);
  const int jt = x >> 5;                        // 0..15
  const int t  = threadIdx.x;
  const int w  = t >> 6, lane = t & 63;

  char* img = ws + (size_t)(bh * 16 + jt) * TS2;
  half8* imgKh = (half8*)img;
  half8* imgKl = imgKh + 1024;
  half8* imgVt = imgKh + 2048;
  float* ksqp  = (float*)(img + 49152); // 128 floats

  const float* Kt = Kp + ((size_t)bh * S_LEN + jt * BN) * HD;
  const float* Vt = Vp + ((size_t)bh * S_LEN + jt * BN) * HD;

  #pragma unroll
  for (int i = 0; i < 8; ++i) {
    const int id  = t + 256 * i;
    const int row = id >> 4;            // 0..127
    const int d4  = id & 15;            // 16B sub-chunk of the 64-half row
    const f32x4 f = *(const f32x4*)(Kt + row * HD + d4 * 4);
    half4 hv, lv;
    float ss = 0.f;
    #pragma unroll
    for (int c = 0; c < 4; ++c) {
      const float fv = f[c];
      const _Float16 hi = (_Float16)fv;
      hv[c] = hi;
      lv[c] = (_Float16)(fv - (float)hi);
      ss += fv * fv;
    }
    const int idx8 = (d4 >> 1) * 128 + row;     // chunk-major, <= 1023
    ((half4*)&imgKh[idx8])[d4 & 1] = hv;
    ((half4*)&imgKl[idx8])[d4 & 1] = lv;
    #pragma unroll
    for (int m = 1; m < 16; m <<= 1) ss += __shfl_xor(ss, m);
    if ((t & 15) == 0) ksqp[row] = ss * (SCALE * LOG2E) - 14.0f;  // bias folded
  }
  // V transpose: lane holds col d=lane (row of V^T); wave w covers k-rows
  // w*32..w*32+31 = k-chunks w*4..w*4+3. Chunk-major: Vt[c][d] at c*64+d.
  float vr[32];
  #pragma unroll
  for (int i = 0; i < 32; ++i) vr[i] = Vt[(w * 32 + i) * HD + lane];
  #pragma unroll
  for (int j = 0; j < 4; ++j) {
    half8 v;
    #pragma unroll
    for (int e = 0; e < 8; ++e) v[e] = (_Float16)vr[j * 8 + e];
    imgVt[(w * 4 + j) * 64 + lane] = v;         // 1KB contiguous per j
  }
}

// ---------------- main kernel ------------------------------------------------
__global__ __launch_bounds__(256, 3)
void rbf_causal_attn(const float* __restrict__ Qp, const char* __restrict__ ws,
                     float* __restrict__ Op) {
  __shared__ __align__(16) char sTile[TS2];    // Khi|Klo|Vt|ksq image

  const int x    = blockIdx.x;                 // 0..767
  const int xcd  = x & 7;
  const int idx  = x >> 3;                     // 0..95
  const int bh   = xcd * 4 + (idx & 3);        // 4 bh per XCD (L2 reuse of ws)
  const int a    = idx >> 2;                   // arc 0..23
  const int t    = threadIdx.x;
  const int w    = t >> 6;
  const int lane = t & 63;
  const int l31  = lane & 31;
  const int l5   = lane >> 5;                  // 0/1

  // 136 j-iters per bh (qt=15..0, qt+1 tiles each); 16 arcs x 6 + 8 arcs x 5
  const int start = (a < 16) ? 6 * a : 96 + 5 * (a - 16);
  const int len   = (a < 16) ? 6 : 5;

  // flattened (qt descending, jt ascending) -> (qt, jt)
  int rem = start, qt = 15;
  while (rem >= qt + 1) { rem -= qt + 1; --qt; }
  int jt = rem;

  const char* wsb = ws + (size_t)bh * 16 * TS2;

  const half8* bKh  = (const half8*)sTile;     // [8 chunks][128 rows]
  const half8* bKl  = bKh + 1024;              // +16KB
  const half8* bVt  = bKh + 2048;              // +32KB: [16 chunks][64 rows]
  const float* bksq = (const float*)(sTile + 49152);

  half8 qh[4], ql[4];   // B-operand Q frags: lane holds row w*32+l31, d-chunk ks*16+l5*8
  float qsq;            // SCALE*LOG2E*|q_row|^2
  f32x16 oacc[2];       // O accumulator (x 2^14), dtile 0/1
  #pragma unroll
  for (int d = 0; d < 2; ++d)
    #pragma unroll
    for (int e = 0; e < 16; ++e) oacc[d][e] = 0.f;

  auto load_q = [&](int qtile) {
    const float* Qg = Qp + ((size_t)bh * S_LEN + (size_t)qtile * BM + w * 32 + l31) * HD;
    float ss = 0.f;
    #pragma unroll
    for (int ks = 0; ks < 4; ++ks) {
      const int d0 = ks * 16 + l5 * 8;
      const f32x4 fa = *(const f32x4*)(Qg + d0);
      const f32x4 fb = *(const f32x4*)(Qg + d0 + 4);
      half8 h, l;
      #pragma unroll
      for (int c = 0; c < 4; ++c) {
        const float va = fa[c], vb = fb[c];
        const _Float16 ha = (_Float16)va, hb = (_Float16)vb;
        h[c] = ha;  h[c + 4] = hb;
        l[c] = (_Float16)(va - (float)ha);
        l[c + 4] = (_Float16)(vb - (float)hb);
        ss += va * va + vb * vb;
      }
      qh[ks] = h;  ql[ks] = l;
    }
    ss += __shfl_xor(ss, 32);   // combine l5 halves -> full row sum
    qsq = ss * (SCALE * LOG2E);
  };

  auto flush = [&](int qtile) {
    #pragma unroll
    for (int dt = 0; dt < 2; ++dt)
      #pragma unroll
      for (int r = 0; r < 16; ++r) {
        const int row = qtile * BM + w * 32 + (r & 3) + 8 * (r >> 2) + 4 * l5;
        atomicAdd(Op + ((size_t)bh * S_LEN + row) * HD + dt * 32 + l31,
                  oacc[dt][r] * 6.103515625e-05f);   // * 2^-14
      }
  };

  auto zacc = [&]() {
    #pragma unroll
    for (int d = 0; d < 2; ++d)
      #pragma unroll
      for (int e = 0; e < 16; ++e) oacc[d][e] = 0.f;
  };

  // issue global->LDS DMA of tile jtile (drained by the following barrier)
  auto stage = [&](int jtile) {
    const char* gt = wsb + (size_t)jtile * TS2;
    #pragma unroll
    for (int i = 0; i < 12; ++i) {            // 48KB K+V
      const int off = w * 12288 + i * 1024;
      __builtin_amdgcn_global_load_lds((const unsigned int*)(gt + off + lane * 16),
                                       (unsigned int*)(sTile + off), 16, 0, 0);
    }
    if (w == 0 && lane < 32)                  // ksq 512B
      __builtin_amdgcn_global_load_lds((const unsigned int*)(gt + 49152 + lane * 16),
                                       (unsigned int*)(sTile + 49152), 16, 0, 0);
  };

  // pack two fp32 -> one u32 of 2 x fp16 (RNE, same numerics as before)
  auto pk = [&](float xx, float yy) -> unsigned int {
    half2v h;
    h[0] = (_Float16)xx;
    h[1] = (_Float16)yy;
    return __builtin_bit_cast(unsigned int, h);
  };

  // ---- building blocks (per 32-row ntile) ----
  // K-frag read, chunk-major: addr = ch*2048 + rr*16 bytes -> lanes with the
  // same l5 read 32 consecutive 16B slots (contiguous 512B run): conflict-free.
  auto QK = [&](int ntile, f32x16& acc) {
    #pragma unroll
    for (int e = 0; e < 16; ++e) acc[e] = 0.f;
    const int rr = ntile * 32 + l31;
    #pragma unroll
    for (int ks = 0; ks < 4; ++ks) {
      const int ch = 2 * ks + l5;
      const half8 kh = bKh[ch * 128 + rr];
      const half8 kl = bKl[ch * 128 + rr];
      acc = __builtin_amdgcn_mfma_f32_32x32x16_f16(kh, qh[ks], acc, 0, 0, 0);
      acc = __builtin_amdgcn_mfma_f32_32x32x16_f16(kh, ql[ks], acc, 0, 0, 0);
      acc = __builtin_amdgcn_mfma_f32_32x32x16_f16(kl, qh[ks], acc, 0, 0, 0);
    }
  };

  // exp2 + optional causal mask (valid only for ntile==w on jt==qt tiles,
  // where the condition reduces to k_local > l31) + pack into PV A-frags.
  // acc[r] = P[k_loc=(r&3)+8*(r>>2)+4*l5][q=l31]; permlane32_swap(vdst=A,vsrc=B)
  // swaps VDST.hi32lanes <-> VSRC.lo32lanes -> pa = {newA0,newA1,newB0,newB1}
  // = P[q=l31][k=16*ks2+8*l5+0..7].
  auto EXPP = [&](int ntile, f32x16& acc, half8& pa0, half8& pa1, bool domask) {
    #pragma unroll
    for (int g = 0; g < 4; ++g) {
      const f32x4 k4 = *(const f32x4*)(bksq + ntile * 32 + 8 * g + 4 * l5);
      #pragma unroll
      for (int rr2 = 0; rr2 < 4; ++rr2) {
        const int reg = g * 4 + rr2;
        const float lg = __builtin_fmaf(C2, acc[reg], -k4[rr2]) - qsq;
        float pv = __builtin_amdgcn_exp2f(lg);
        if (domask) {
          const int nloc = 8 * g + 4 * l5 + rr2;
          if (nloc > l31) pv = 0.f;
        }
        acc[reg] = pv;
      }
    }
    #pragma unroll
    for (int ks2 = 0; ks2 < 2; ++ks2) {
      const unsigned int a0 = pk(acc[8 * ks2 + 0], acc[8 * ks2 + 1]);
      const unsigned int a1 = pk(acc[8 * ks2 + 2], acc[8 * ks2 + 3]);
      const unsigned int b0 = pk(acc[8 * ks2 + 4], acc[8 * ks2 + 5]);
      const unsigned int b1 = pk(acc[8 * ks2 + 6], acc[8 * ks2 + 7]);
      const uint2v r0 = __builtin_amdgcn_permlane32_swap(a0, b0, false, false);
      const uint2v r1 = __builtin_amdgcn_permlane32_swap(a1, b1, false, false);
      uint4v wv;
      wv[0] = r0[0];  wv[1] = r1[0];
      wv[2] = r0[1];  wv[3] = r1[1];
      if (ks2 == 0) pa0 = __builtin_bit_cast(half8, wv);
      else          pa1 = __builtin_bit_cast(half8, wv);
    }
  };

  // V-frag read, chunk-major: addr = ch*1024 + rr*16 -> contiguous runs.
  auto PVF = [&](int ntile, half8 pa0v, half8 pa1v) {
    #pragma unroll
    for (int ks2 = 0; ks2 < 2; ++ks2) {
      const half8 pa = ks2 ? pa1v : pa0v;
      const int ks = ntile * 2 + ks2;
      const int ch = 2 * ks + l5;
      #pragma unroll
      for (int dt = 0; dt < 2; ++dt) {
        const int rr = dt * 32 + l31;
        const half8 vt = bVt[ch * 64 + rr];
        oacc[dt] = __builtin_amdgcn_mfma_f32_32x32x16_f16(pa, vt, oacc[dt], 0, 0, 0);
      }
    }
  };

  load_q(qt);

  bool newq = false;
  #pragma unroll 1
  for (int step = 0; step < len; ++step) {
    stage(jt);   // previous iteration's end barrier protects sTile

    // q-tile boundary bookkeeping: overlaps the in-flight DMA
    if (newq) { flush(qt + 1); zacc(); load_q(qt); newq = false; }

    __syncthreads();   // drains vmcnt -> tile image ready

    if (jt < qt) {
      // ---- clean tile: software-pipelined 4-ntile body (one basic block) ----
      f32x16 accA, accB;
      half8 pa0, pa1;
      QK(0, accA);
      QK(1, accB);  EXPP(0, accA, pa0, pa1, false);  PVF(0, pa0, pa1);
      QK(2, accA);  EXPP(1, accB, pa0, pa1, false);  PVF(1, pa0, pa1);
      QK(3, accB);  EXPP(2, accA, pa0, pa1, false);  PVF(2, pa0, pa1);
                    EXPP(3, accB, pa0, pa1, false);  PVF(3, pa0, pa1);
    } else {
      // ---- diagonal tile (jt==qt): ntile>w fully masked -> skipped;
      //      ntile==w needs the per-element causal mask ----
      for (int ntile = 0; ntile <= w; ++ntile) {
        f32x16 acc;
        half8 pa0, pa1;
        QK(ntile, acc);
        EXPP(ntile, acc, pa0, pa1, ntile == w);
        PVF(ntile, pa0, pa1);
      }
    }

    __syncthreads();   // all waves done reading sTile before next stage

    ++jt;
    if (jt > qt) { jt = 0; --qt; newq = true; }
  }
  flush(newq ? qt + 1 : qt);
}

extern "C" void kernel_launch(void* const* d_in, const int* in_sizes, int n_in,
                              void* d_out, int out_size, void* d_ws, size_t ws_size,
                              hipStream_t stream) {
  const float* q = (const float*)d_in[0];
  const float* k = (const float*)d_in[1];
  const float* v = (const float*)d_in[2];
  float* o = (float*)d_out;
  hipMemsetAsync(d_out, 0, (size_t)out_size * sizeof(float), stream);
  preconvert<<<dim3(512), dim3(256), 0, stream>>>(k, v, (char*)d_ws);
  rbf_causal_attn<<<dim3(768), dim3(256), 0, stream>>>(q, (const char*)d_ws, o);
}